// Round 12
// baseline (353.380 us; speedup 1.0000x reference)
//
#include <hip/hip_runtime.h>
#include <stdint.h>

// Problem constants
#define E_DIM 1024
#define KAUG 1056            // 1024 + 16 (LoRA) + 1 (bias) + 15 pad
#define N_HEADS 16
#define HD 64
#define R_LORA 16
#define T_LEN 2048
#define B_SZ 2
#define S_LEN 2048
#define NROW 4096            // T*B == S*B
// q pre-scale: (1/sqrt(64)) * log2(e)  -> softmax becomes exp2(score)
#define Q_SCALE 0.1803368801111204f

#define XG_N ((size_t)NROW * KAUG)
#define WG_N ((size_t)E_DIM * KAUG)
#define HSZ  ((size_t)B_SZ * N_HEADS * T_LEN * HD)

typedef unsigned short USH;
typedef __bf16 bf16x8 __attribute__((ext_vector_type(8)));
typedef unsigned short ushort8 __attribute__((ext_vector_type(8)));
typedef float  f32x4  __attribute__((ext_vector_type(4)));
typedef float  f32x16 __attribute__((ext_vector_type(16)));
typedef unsigned int u32x2 __attribute__((ext_vector_type(2)));
typedef unsigned int u32x4 __attribute__((ext_vector_type(4)));

__device__ __forceinline__ USH f2bf(float f) {
    uint32_t u = __builtin_bit_cast(uint32_t, f);
    return (USH)((u + 0x7FFFu + ((u >> 16) & 1u)) >> 16);
}
__device__ __forceinline__ float bf2f(USH s) {
    uint32_t u = ((uint32_t)s) << 16;
    return __builtin_bit_cast(float, u);
}
__device__ __forceinline__ void async_cp16(const void* g, void* l) {
    __builtin_amdgcn_global_load_lds(
        (const __attribute__((address_space(1))) void*)g,
        (__attribute__((address_space(3))) void*)l, 16, 0, 0);
}
// pack hi16(x), hi16(y) -> dword (bf16 truncation; y in high half)
__device__ __forceinline__ uint32_t pack_bf_trunc(float x, float y) {
    return __builtin_amdgcn_perm(__builtin_bit_cast(uint32_t, y),
                                 __builtin_bit_cast(uint32_t, x), 0x07060302u);
}
// 8 floats -> bf16x8 with RNE rounding (matches f2bf store path)
__device__ __forceinline__ bf16x8 cvt8(float4 a, float4 b) {
    ushort8 u;
    u[0] = f2bf(a.x); u[1] = f2bf(a.y); u[2] = f2bf(a.z); u[3] = f2bf(a.w);
    u[4] = f2bf(b.x); u[5] = f2bf(b.y); u[6] = f2bf(b.z); u[7] = f2bf(b.w);
    return __builtin_bit_cast(bf16x8, u);
}

// ---------------------------------------------------------------------------
// lora_aug v2: MFMA-based. Block = 16 rows, 4 waves K-split (256 k each).
// ---------------------------------------------------------------------------
__global__ __launch_bounds__(256) void lora_aug_x3_kernel(
    const float* __restrict__ Xq, const float* __restrict__ Xk,
    const float* __restrict__ Xv,
    const float* __restrict__ laq, const float* __restrict__ lak,
    const float* __restrict__ lav, USH* __restrict__ Xg_base) {
    int n0 = blockIdx.x * 16, y = blockIdx.y, tid = threadIdx.x;
    const float* X  = (y == 0) ? Xq : (y == 1) ? Xk : Xv;
    const float* la = (y == 0) ? laq : (y == 1) ? lak : lav;
    USH* Xg = Xg_base + (size_t)y * XG_N;

    int w = tid >> 6, lane = tid & 63, quad = lane >> 4, l16 = lane & 15;

    const float* xrow = X + (size_t)(n0 + l16) * E_DIM;
    const float* lrow = la + (size_t)l16 * E_DIM;
    USH* grow = Xg + (size_t)(n0 + l16) * KAUG;

    const f32x4 fzero = {0.f, 0.f, 0.f, 0.f};
    f32x4 acc = fzero;

#pragma unroll
    for (int i = 0; i < 8; ++i) {
        int k = w * 256 + i * 32 + quad * 8;
        bf16x8 af = cvt8(*(const float4*)(xrow + k), *(const float4*)(xrow + k + 4));
        *(bf16x8*)(grow + k) = af;                       // bf16 cast-write
        bf16x8 bf_ = cvt8(*(const float4*)(lrow + k), *(const float4*)(lrow + k + 4));
        acc = __builtin_amdgcn_mfma_f32_16x16x32_bf16(af, bf_, acc, 0, 0, 0);
    }

    // combine 4 wave-partials: acc[r] = XA[row = quad*4+r][col = l16] partial
    __shared__ float red[4][16][17];
#pragma unroll
    for (int r = 0; r < 4; ++r) red[w][quad * 4 + r][l16] = acc[r];
    __syncthreads();

    int row = tid >> 4, col = tid & 15;
    float v = red[0][row][col] + red[1][row][col] + red[2][row][col] + red[3][row][col];
    USH* trow = Xg + (size_t)(n0 + row) * KAUG + 1024;
    trow[col] = f2bf(v);                                 // XA cols 1024..1039
    trow[16 + col] = (col == 0) ? f2bf(1.0f) : (USH)0;   // bias col 1040, pad 0
}

// ---------------------------------------------------------------------------
// lora_a v2 (O-input tails): same MFMA structure; A-frags load bf16 Xg rows
// directly (already cast by flash). grid (NROW/16) = 256 blocks.
// ---------------------------------------------------------------------------
__global__ __launch_bounds__(256) void lora_a_bf16_kernel(
    USH* __restrict__ Xg, const float* __restrict__ la) {
    int n0 = blockIdx.x * 16, tid = threadIdx.x;
    int w = tid >> 6, lane = tid & 63, quad = lane >> 4, l16 = lane & 15;

    const USH* grow = Xg + (size_t)(n0 + l16) * KAUG;
    const float* lrow = la + (size_t)l16 * E_DIM;

    const f32x4 fzero = {0.f, 0.f, 0.f, 0.f};
    f32x4 acc = fzero;

#pragma unroll
    for (int i = 0; i < 8; ++i) {
        int k = w * 256 + i * 32 + quad * 8;
        bf16x8 af = *(const bf16x8*)(grow + k);
        bf16x8 bf_ = cvt8(*(const float4*)(lrow + k), *(const float4*)(lrow + k + 4));
        acc = __builtin_amdgcn_mfma_f32_16x16x32_bf16(af, bf_, acc, 0, 0, 0);
    }

    __shared__ float red[4][16][17];
#pragma unroll
    for (int r = 0; r < 4; ++r) red[w][quad * 4 + r][l16] = acc[r];
    __syncthreads();

    int row = tid >> 4, col = tid & 15;
    float v = red[0][row][col] + red[1][row][col] + red[2][row][col] + red[3][row][col];
    USH* trow = Xg + (size_t)(n0 + row) * KAUG + 1024;
    trow[col] = f2bf(v);
    trow[16 + col] = (col == 0) ? f2bf(1.0f) : (USH)0;
}

// ---------------------------------------------------------------------------
// Fused weight augment for all four projections. grid (E_DIM, 4): q,k,v,o.
// ---------------------------------------------------------------------------
__global__ __launch_bounds__(256) void aug_w4_kernel(
    const float* __restrict__ Wq, const float* __restrict__ lbq, const float* __restrict__ bq,
    const float* __restrict__ Wk, const float* __restrict__ lbk, const float* __restrict__ bk_,
    const float* __restrict__ Wv, const float* __restrict__ lbv, const float* __restrict__ bv_,
    const float* __restrict__ Wo, const float* __restrict__ lbo, const float* __restrict__ bo,
    USH* __restrict__ Wg_base) {
    int e = blockIdx.x, y = blockIdx.y, tid = threadIdx.x;
    const float* W    = (y == 0) ? Wq : (y == 1) ? Wk : (y == 2) ? Wv : Wo;
    const float* lb   = (y == 0) ? lbq : (y == 1) ? lbk : (y == 2) ? lbv : lbo;
    const float* bias = (y == 0) ? bq : (y == 1) ? bk_ : (y == 2) ? bv_ : bo;
    USH* Wg = Wg_base + (size_t)y * WG_N;

    float4 v = *(const float4*)(W + (size_t)e * E_DIM + tid * 4);
    ushort4 o;
    o.x = f2bf(v.x); o.y = f2bf(v.y); o.z = f2bf(v.z); o.w = f2bf(v.w);
    *(ushort4*)(Wg + (size_t)e * KAUG + tid * 4) = o;
    if (tid < 32) {
        float t = (tid < R_LORA) ? lb[(size_t)e * R_LORA + tid]
                                 : (tid == R_LORA ? bias[e] : 0.0f);
        Wg[(size_t)e * KAUG + 1024 + tid] = f2bf(t);
    }
}

// ---------------------------------------------------------------------------
// Batched q/k/v GEMM, 128x128 tile, grid (8, 32, 3) = 768. Double-buffered
// LDS + prefetch-before-compute + ONE barrier per K-step.
// ---------------------------------------------------------------------------
__global__ __launch_bounds__(256) void gemm_qkv_kernel(
    const USH* __restrict__ Xg_base, const USH* __restrict__ Wg_base,
    USH* __restrict__ qkv_base) {
    __shared__ __align__(16) USH As[2][128 * 32];
    __shared__ __align__(16) USH Bs[2][128 * 32];

    int orig = blockIdx.x + (blockIdx.y << 3) + blockIdx.z * 256;   // grid 8x32x3
    int v_ = (orig & 7) * 96 + (orig >> 3);                          // bijective, 768%8==0
    int e0 = (v_ & 7) * 128, n0 = ((v_ >> 3) & 31) * 128, z = v_ >> 8;

    const USH* Xg = Xg_base + (size_t)z * XG_N;
    const USH* Wg = Wg_base + (size_t)z * WG_N;
    USH* out = qkv_base + (size_t)z * HSZ;
    float scale = (z == 0) ? Q_SCALE : 1.0f;

    int tid = threadIdx.x;
    int wid = tid >> 6, lane = tid & 63, quad = lane >> 4, l16 = lane & 15;
    int wm = wid & 1, wn = wid >> 1;

    int r0 = wid * 16 + (lane >> 2);
    int k8 = (lane & 3) * 8;

    f32x4 acc[4][4];
    const f32x4 fzero = {0.f, 0.f, 0.f, 0.f};
#pragma unroll
    for (int i = 0; i < 4; ++i)
#pragma unroll
        for (int j = 0; j < 4; ++j) acc[i][j] = fzero;

    // prologue: stage kt=0 into buf 0
    async_cp16(Xg + (size_t)(n0 + r0) * KAUG + k8,       As[0] + (wid * 16) * 32);
    async_cp16(Xg + (size_t)(n0 + 64 + r0) * KAUG + k8,  As[0] + (64 + wid * 16) * 32);
    async_cp16(Wg + (size_t)(e0 + r0) * KAUG + k8,       Bs[0] + (wid * 16) * 32);
    async_cp16(Wg + (size_t)(e0 + 64 + r0) * KAUG + k8,  Bs[0] + (64 + wid * 16) * 32);
    __syncthreads();

    int cur = 0;
    for (int kt = 0; kt < KAUG; kt += 32, cur ^= 1) {
        if (kt + 32 < KAUG) {
            int kn = kt + 32;
            async_cp16(Xg + (size_t)(n0 + r0) * KAUG + kn + k8,       As[cur ^ 1] + (wid * 16) * 32);
            async_cp16(Xg + (size_t)(n0 + 64 + r0) * KAUG + kn + k8,  As[cur ^ 1] + (64 + wid * 16) * 32);
            async_cp16(Wg + (size_t)(e0 + r0) * KAUG + kn + k8,       Bs[cur ^ 1] + (wid * 16) * 32);
            async_cp16(Wg + (size_t)(e0 + 64 + r0) * KAUG + kn + k8,  Bs[cur ^ 1] + (64 + wid * 16) * 32);
        }

        bf16x8 af[4], bfr[4];
#pragma unroll
        for (int i = 0; i < 4; ++i)
            af[i] = *(const bf16x8*)&As[cur][(wm * 64 + i * 16 + l16) * 32 + quad * 8];
#pragma unroll
        for (int j = 0; j < 4; ++j)
            bfr[j] = *(const bf16x8*)&Bs[cur][(wn * 64 + j * 16 + l16) * 32 + quad * 8];
#pragma unroll
        for (int i = 0; i < 4; ++i)
#pragma unroll
            for (int j = 0; j < 4; ++j)
                acc[i][j] = __builtin_amdgcn_mfma_f32_16x16x32_bf16(
                    af[i], bfr[j], acc[i][j], 0, 0, 0);

        // one barrier: drains prefetch (landed under compute) + releases cur
        __syncthreads();
    }

#pragma unroll
    for (int i = 0; i < 4; ++i) {
#pragma unroll
        for (int j = 0; j < 4; ++j) {
#pragma unroll
            for (int r = 0; r < 4; ++r) {
                int nr = n0 + wm * 64 + i * 16 + quad * 4 + r;
                int ec = e0 + wn * 64 + j * 16 + l16;
                float v = acc[i][j][r] * scale;
                int b = nr & 1, h = ec >> 6, d = ec & 63;
                if (z != 2) {
                    int t = nr >> 1;
                    out[(((size_t)(b * 16 + h) * T_LEN + t) << 6) + d] = f2bf(v);
                } else {
                    int s = nr >> 1;
                    out[(((size_t)(b * 16 + h) * HD + d) << 11) + s] = f2bf(v);
                }
            }
        }
    }
}

// ---------------------------------------------------------------------------
// O-projection GEMM -> fp32 d_out. grid (8, 64) = 512 blocks. Pipelined
// single-barrier loop (dbuf LDS: 2x(4+8) = 24 KB).
// ---------------------------------------------------------------------------
__global__ __launch_bounds__(256) void gemm_o_kernel(
    const USH* __restrict__ Xg, const USH* __restrict__ Wg,
    float* __restrict__ out) {
    __shared__ __align__(16) USH As[2][64 * 32];
    __shared__ __align__(16) USH Bs[2][128 * 32];

    int orig = blockIdx.x + (blockIdx.y << 3);          // grid 8x64
    int v_ = ((orig & 7) << 6) + (orig >> 3);           // 64 blocks/XCD
    int e0 = (v_ & 7) * 128, n0 = (v_ >> 3) * 64;

    int tid = threadIdx.x;
    int wid = tid >> 6, lane = tid & 63, quad = lane >> 4, l16 = lane & 15;
    int wm = wid & 1, wn = wid >> 1;
    int r0 = wid * 16 + (lane >> 2);
    int k8 = (lane & 3) * 8;

    f32x4 acc[2][4];
    const f32x4 fzero = {0.f, 0.f, 0.f, 0.f};
#pragma unroll
    for (int i = 0; i < 2; ++i)
#pragma unroll
        for (int j = 0; j < 4; ++j) acc[i][j] = fzero;

    // prologue: stage kt=0 into buf 0
    async_cp16(Xg + (size_t)(n0 + r0) * KAUG + k8,       As[0] + (wid * 16) * 32);
    async_cp16(Wg + (size_t)(e0 + r0) * KAUG + k8,       Bs[0] + (wid * 16) * 32);
    async_cp16(Wg + (size_t)(e0 + 64 + r0) * KAUG + k8,  Bs[0] + (64 + wid * 16) * 32);
    __syncthreads();

    int cur = 0;
    for (int kt = 0; kt < KAUG; kt += 32, cur ^= 1) {
        if (kt + 32 < KAUG) {
            int kn = kt + 32;
            async_cp16(Xg + (size_t)(n0 + r0) * KAUG + kn + k8,       As[cur ^ 1] + (wid * 16) * 32);
            async_cp16(Wg + (size_t)(e0 + r0) * KAUG + kn + k8,       Bs[cur ^ 1] + (wid * 16) * 32);
            async_cp16(Wg + (size_t)(e0 + 64 + r0) * KAUG + kn + k8,  Bs[cur ^ 1] + (64 + wid * 16) * 32);
        }

        bf16x8 af[2], bfr[4];
#pragma unroll
        for (int i = 0; i < 2; ++i)
            af[i] = *(const bf16x8*)&As[cur][(wm * 32 + i * 16 + l16) * 32 + quad * 8];
#pragma unroll
        for (int j = 0; j < 4; ++j)
            bfr[j] = *(const bf16x8*)&Bs[cur][(wn * 64 + j * 16 + l16) * 32 + quad * 8];
#pragma unroll
        for (int i = 0; i < 2; ++i)
#pragma unroll
            for (int j = 0; j < 4; ++j)
                acc[i][j] = __builtin_amdgcn_mfma_f32_16x16x32_bf16(
                    af[i], bfr[j], acc[i][j], 0, 0, 0);

        __syncthreads();
    }

#pragma unroll
    for (int i = 0; i < 2; ++i)
#pragma unroll
        for (int j = 0; j < 4; ++j)
#pragma unroll
            for (int r = 0; r < 4; ++r) {
                int nr = n0 + wm * 32 + i * 16 + quad * 4 + r;
                int ec = e0 + wn * 64 + j * 16 + l16;
                out[(size_t)nr * E_DIM + ec] = acc[i][j][r];
            }
}

// ---------------------------------------------------------------------------
// Flash v14 (frozen): 32x32 MFMA, in-register softmax (T12), PV-lag (T15),
// fragment-major K/V staging (0 bank conflicts), one barrier/iter, XCD chunk.
// 4 waves x 32 t-rows, grid (T/128, B*H) = 512 blocks, LDS 32 KB.
// ---------------------------------------------------------------------------
__global__ __launch_bounds__(256, 2) void flash_mfma_kernel(
    const USH* __restrict__ qp, const USH* __restrict__ kp,
    const USH* __restrict__ vpt, USH* __restrict__ ohg,
    float* __restrict__ lbuf) {
    __shared__ __align__(16) USH Ks[2][4096];   // 8 frags x 512 USH (1KB each)
    __shared__ __align__(16) USH Vs[2][4096];

    int orig = blockIdx.x + (blockIdx.y << 4);  // grid 16x32
    int v_ = ((orig & 7) << 6) + (orig >> 3);   // 64 blocks/XCD chunk
    int t0 = (v_ & 15) * 128, bh = v_ >> 4;     // chunk c -> heads [4c, 4c+4)

    int tid = threadIdx.x, w = tid >> 6, lane = tid & 63;
    int lo = lane & 31, hi = lane >> 5;
    size_t headO = (size_t)bh * (T_LEN * HD);
    int t_base = t0 + w * 32;

    // Q fragments direct from global (B-operand: n=t=lo, k=kb*16+hi*8+e)
    bf16x8 bq[4];
    {
        const USH* qrow = qp + headO + (size_t)(t_base + lo) * HD + hi * 8;
#pragma unroll
        for (int kb = 0; kb < 4; ++kb)
            bq[kb] = *(const bf16x8*)(qrow + kb * 16);
    }

    // prologue: stage K[0] only (V[0] staged inside iter 0).
#pragma unroll
    for (int c = 0; c < 2; ++c) {
        int f = w * 2 + c;
        async_cp16(kp + headO + (size_t)((f >> 2) * 32 + lo) * HD + (f & 3) * 16 + hi * 8,
                   &Ks[0][f * 512]);
    }
    __syncthreads();

    const f32x16 z16 = {0,0,0,0,0,0,0,0,0,0,0,0,0,0,0,0};
    f32x16 o0 = z16, o1 = z16;
    float lsum = 0.f;
    bf16x8 pa_prev[4];          // P(i-1) A-frags, static-indexed (rule #20)

    for (int it = 0; it < S_LEN / 64; ++it) {
        int cur = it & 1;
        // prefetch K[it+1] -> Ks[cur^1]; stage V[it] -> Vs[cur]
        if (it + 1 < S_LEN / 64) {
            int sn = (it + 1) * 64;
#pragma unroll
            for (int c = 0; c < 2; ++c) {
                int f = w * 2 + c;
                async_cp16(kp + headO + (size_t)(sn + (f >> 2) * 32 + lo) * HD + (f & 3) * 16 + hi * 8,
                           &Ks[cur ^ 1][f * 512]);
            }
        }
        {
            int s0 = it * 64;
#pragma unroll
            for (int c = 0; c < 2; ++c) {
                int f = w * 2 + c;
                async_cp16(vpt + headO + (size_t)((f >> 2) * 32 + lo) * S_LEN + s0 + (f & 3) * 16 + hi * 8,
                           &Vs[cur][f * 512]);
            }
        }

        // QK^T swapped: sc[st] = 32x32 tile, C[row=s_local][col=t_local=lo]
        f32x16 sc0 = z16, sc1 = z16;
        __builtin_amdgcn_s_setprio(1);
#pragma unroll
        for (int kb = 0; kb < 4; ++kb) {
            bf16x8 ak0 = *(const bf16x8*)&Ks[cur][(0 * 4 + kb) * 512 + lane * 8];
            sc0 = __builtin_amdgcn_mfma_f32_32x32x16_bf16(ak0, bq[kb], sc0, 0, 0, 0);
        }
#pragma unroll
        for (int kb = 0; kb < 4; ++kb) {
            bf16x8 ak1 = *(const bf16x8*)&Ks[cur][(1 * 4 + kb) * 512 + lane * 8];
            sc1 = __builtin_amdgcn_mfma_f32_32x32x16_bf16(ak1, bq[kb], sc1, 0, 0, 0);
        }

        // PV(it-1): pa_prev (regs) x V(it-1) from Vs[cur^1].
        if (it > 0) {
#pragma unroll
            for (int ks = 0; ks < 4; ++ks) {
                bf16x8 bv0 = *(const bf16x8*)&Vs[cur ^ 1][(0 * 4 + ks) * 512 + lane * 8];
                o0 = __builtin_amdgcn_mfma_f32_32x32x16_bf16(pa_prev[ks], bv0, o0, 0, 0, 0);
            }
#pragma unroll
            for (int ks = 0; ks < 4; ++ks) {
                bf16x8 bv1 = *(const bf16x8*)&Vs[cur ^ 1][(1 * 4 + ks) * 512 + lane * 8];
                o1 = __builtin_amdgcn_mfma_f32_32x32x16_bf16(pa_prev[ks], bv1, o1, 0, 0, 0);
            }
        }
        __builtin_amdgcn_s_setprio(0);

        // softmax(it): exp2 in place, partial sums
        float ls0 = 0.f, ls1 = 0.f, ls2 = 0.f, ls3 = 0.f;
#pragma unroll
        for (int r = 0; r < 16; ++r) {
            float p0 = __builtin_amdgcn_exp2f(sc0[r]);
            float p1 = __builtin_amdgcn_exp2f(sc1[r]);
            sc0[r] = p0; sc1[r] = p1;
            if ((r & 3) == 0)      { ls0 += p0; ls0 += p1; }
            else if ((r & 3) == 1) { ls1 += p0; ls1 += p1; }
            else if ((r & 3) == 2) { ls2 += p0; ls2 += p1; }
            else                   { ls3 += p0; ls3 += p1; }
        }
        lsum += (ls0 + ls1) + (ls2 + ls3);

        // P(it) -> pa_prev for next iter (T12 cvt_pk + permlane32_swap)
#pragma unroll
        for (int st = 0; st < 2; ++st) {
#pragma unroll
            for (int hh = 0; hh < 2; ++hh) {
                const f32x16& s_ = st ? sc1 : sc0;
                uint32_t a0 = pack_bf_trunc(s_[hh * 8 + 0], s_[hh * 8 + 1]);
                uint32_t a1 = pack_bf_trunc(s_[hh * 8 + 2], s_[hh * 8 + 3]);
                uint32_t a2 = pack_bf_trunc(s_[hh * 8 + 4], s_[hh * 8 + 5]);
                uint32_t a3 = pack_bf_trunc(s_[hh * 8 + 6], s_[hh * 8 + 7]);
                u32x2 r02 = __builtin_amdgcn_permlane32_swap(a0, a2, false, false);
                u32x2 r13 = __builtin_amdgcn_permlane32_swap(a1, a3, false, false);
                u32x4 pd = {r02[0], r13[0], r02[1], r13[1]};
                pa_prev[st * 2 + hh] = __builtin_bit_cast(bf16x8, pd);
            }
        }

        // one barrier/iter: drains K[it+1] + V[it] staging, releases buffers
        __syncthreads();
    }

    // epilogue: PV(31) from Vs[1]
    {
#pragma unroll
        for (int ks = 0; ks < 4; ++ks) {
            bf16x8 bv0 = *(const bf16x8*)&Vs[1][(0 * 4 + ks) * 512 + lane * 8];
            o0 = __builtin_amdgcn_mfma_f32_32x32x16_bf16(pa_prev[ks], bv0, o0, 0, 0, 0);
        }
#pragma unroll
        for (int ks = 0; ks < 4; ++ks) {
            bf16x8 bv1 = *(const bf16x8*)&Vs[1][(1 * 4 + ks) * 512 + lane * 8];
            o1 = __builtin_amdgcn_mfma_f32_32x32x16_bf16(pa_prev[ks], bv1, o1, 0, 0, 0);
        }
    }

    // lane owns full row t = t_base + lo split with partner: combine halves
    lsum += __shfl_xor(lsum, 32, 64);
    float rinv = 1.0f / lsum;

    int b = bh >> 4, h = bh & 15;
    float inv[16];
#pragma unroll
    for (int r = 0; r < 16; ++r) {
        int rr = (r & 3) + 8 * (r >> 2) + 4 * hi;    // t-local of o[*][r]
        inv[r] = __shfl(rinv, rr, 64);               // lane rr holds that t
    }
#pragma unroll
    for (int r = 0; r < 16; ++r) {
        int t = t_base + (r & 3) + 8 * (r >> 2) + 4 * hi;
        size_t nrow = (size_t)(t * 2 + b) * KAUG + h * 64;
        ohg[nrow + lo]      = f2bf(o0[r] * inv[r]);
        ohg[nrow + 32 + lo] = f2bf(o1[r] * inv[r]);
    }
    if (lane < 32)
        lbuf[(size_t)bh * T_LEN + t_base + lane] = rinv;   // store 1/lsum
}

// ---------------------------------------------------------------------------
// attnw v9 = v6 structure (128t x 64s, grid 1024, 16 KB K LDS per head-pair
// buffer, Q/il direct-to-register) with heads processed in PAIRS: each
// iteration computes heads 2p, 2p+1 (independent chains -> head 0's exp2/fma
// VALU pass overlaps head 1's Q loads + MFMA burst on separate pipes) and
// prefetches the next pair's K. Halves barrier count 16 -> 8. LDS 32 KB,
// launch_bounds(256,4) -> 4 blocks/CU (16 waves/CU, same TLP as v6).
// v8's Q-LDS staging REVERTED (cost occupancy + FETCH).
// ---------------------------------------------------------------------------
__global__ __launch_bounds__(256, 4) void attnw_mfma_kernel(
    const USH* __restrict__ qp, const USH* __restrict__ kp,
    const float* __restrict__ lbuf, float* __restrict__ aw) {
    __shared__ __align__(16) USH Ks[2][2][4096];   // [pair-buf][head-in-pair]

    int orig = blockIdx.x + (blockIdx.y << 5) + (blockIdx.z << 9);  // grid 32x16x2
    int v_ = ((orig & 7) << 7) + (orig >> 3);                       // 128 blocks/XCD
    int s0 = (v_ & 31) * 64, t0 = ((v_ >> 5) & 15) * 128, b = v_ >> 9;

    int tid = threadIdx.x, w = tid >> 6, lane = tid & 63;
    int quad = lane >> 4, l16 = lane & 15;

    const f32x4 fzero = {0.f, 0.f, 0.f, 0.f};
    f32x4 acc[2][4];
#pragma unroll
    for (int i2 = 0; i2 < 2; ++i2)
#pragma unroll
        for (int j = 0; j < 4; ++j) acc[i2][j] = fzero;

    size_t head0 = (size_t)(b * 16) * (T_LEN * HD);

    // prologue: stage K for heads 0,1 into pair-buffer 0
#pragma unroll
    for (int hh = 0; hh < 2; ++hh)
#pragma unroll
        for (int half = 0; half < 2; ++half)
            async_cp16(kp + head0 + (size_t)hh * (T_LEN * HD)
                           + (size_t)(s0 + w * 16 + l16) * HD + half * 32 + quad * 8,
                       &Ks[0][hh][w * 1024 + half * 512]);
    __syncthreads();

    for (int p = 0; p < N_HEADS / 2; ++p) {
        int cur = p & 1;

        // prefetch next pair's K into the other pair-buffer
        if (p + 1 < N_HEADS / 2) {
#pragma unroll
            for (int hh = 0; hh < 2; ++hh)
#pragma unroll
                for (int half = 0; half < 2; ++half)
                    async_cp16(kp + head0 + (size_t)(2 * p + 2 + hh) * (T_LEN * HD)
                                   + (size_t)(s0 + w * 16 + l16) * HD + half * 32 + quad * 8,
                               &Ks[cur ^ 1][hh][w * 1024 + half * 512]);
        }

        // two independent head computations per barrier interval
#pragma unroll
        for (int hh = 0; hh < 2; ++hh) {
            int h = 2 * p + hh;
            size_t head = head0 + (size_t)h * (T_LEN * HD);

            // Q fragments direct from global (A-operand; rows wave-private)
            bf16x8 aq[2][2];
#pragma unroll
            for (int i2 = 0; i2 < 2; ++i2) {
                const USH* qrow = qp + head + (size_t)(t0 + w * 32 + i2 * 16 + l16) * HD + quad * 8;
                aq[i2][0] = *(const bf16x8*)qrow;
                aq[i2][1] = *(const bf16x8*)(qrow + 32);
            }

            float il[2][4];
#pragma unroll
            for (int i2 = 0; i2 < 2; ++i2)
#pragma unroll
                for (int r = 0; r < 4; ++r) {
                    int t = t0 + w * 32 + i2 * 16 + quad * 4 + r;
                    il[i2][r] = lbuf[(size_t)(b * 16 + h) * T_LEN + t];   // 1/lsum
                }

            bf16x8 bk[4][2];
#pragma unroll
            for (int j = 0; j < 4; ++j)
#pragma unroll
                for (int half = 0; half < 2; ++half)
                    bk[j][half] = *(const bf16x8*)&Ks[cur][hh][j * 1024 + half * 512 + quad * 128 + l16 * 8];

#pragma unroll
            for (int i2 = 0; i2 < 2; ++i2) {
                // MFMA burst: 4 score tiles back-to-back
                f32x4 sc[4];
#pragma unroll
                for (int j = 0; j < 4; ++j) {
                    f32x4 s = __builtin_amdgcn_mfma_f32_16x16x32_bf16(aq[i2][0], bk[j][0], fzero, 0, 0, 0);
                    sc[j] = __builtin_amdgcn_mfma_f32_16x16x32_bf16(aq[i2][1], bk[j][1], s, 0, 0, 0);
                }
                // one exp2/fma pass
#pragma unroll
                for (int j = 0; j < 4; ++j)
#pragma unroll
                    for (int r = 0; r < 4; ++r)
                        acc[i2][j][r] += __builtin_amdgcn_exp2f(sc[j][r]) * il[i2][r];
            }
        }

        // one barrier per PAIR: drains next pair's staging + releases cur
        __syncthreads();
    }

    const float inv_h = 1.0f / (float)N_HEADS;
#pragma unroll
    for (int i2 = 0; i2 < 2; ++i2)
#pragma unroll
        for (int j = 0; j < 4; ++j)
#pragma unroll
            for (int r = 0; r < 4; ++r) {
                int t = t0 + w * 32 + i2 * 16 + quad * 4 + r;
                aw[(size_t)b * T_LEN * S_LEN + (size_t)t * S_LEN + s0 + j * 16 + l16] =
                    acc[i2][j][r] * inv_h;
            }
}

// ---------------------------------------------------------------------------
extern "C" void kernel_launch(void* const* d_in, const int* in_sizes, int n_in,
                              void* d_out, int out_size, void* d_ws, size_t ws_size,
                              hipStream_t stream) {
    (void)in_sizes; (void)n_in; (void)out_size; (void)ws_size;

    const float* query = (const float*)d_in[0];
    const float* key_  = (const float*)d_in[1];
    const float* value = (const float*)d_in[2];
    const float* q_w = (const float*)d_in[3],  *q_b = (const float*)d_in[4];
    const float* q_la = (const float*)d_in[5], *q_lb = (const float*)d_in[6];
    const float* k_w = (const float*)d_in[7],  *k_b = (const float*)d_in[8];
    const float* k_la = (const float*)d_in[9], *k_lb = (const float*)d_in[10];
    const float* v_w = (const float*)d_in[11], *v_b = (const float*)d_in[12];
    const float* v_la = (const float*)d_in[13], *v_lb = (const float*)d_in[14];
    const float* o_w = (const float*)d_in[15], *o_b = (const float*)d_in[16];
    const float* o_la = (const float*)d_in[17], *o_lb = (const float*)d_in[18];

    USH* Xg   = (USH*)d_ws;                 // 3 * NROW*KAUG
    USH* Wg   = Xg + 3 * XG_N;              // 4 * E_DIM*KAUG
    USH* qkv  = Wg + 4 * WG_N;              // 3 * HSZ
    USH* qp   = qkv;
    USH* kp   = qkv + HSZ;
    USH* vpt  = qkv + 2 * HSZ;
    float* lbuf = (float*)(qkv + 3 * HSZ);

    float* out = (float*)d_out;                       // (T,B,E) fp32
    float* aw  = out + (size_t)T_LEN * B_SZ * E_DIM;  // (B,T,S) fp32

    dim3 blk(256);

    lora_aug_x3_kernel<<<dim3(NROW / 16, 3), blk, 0, stream>>>(
        query, key_, value, q_la, k_la, v_la, Xg);
    aug_w4_kernel<<<dim3(E_DIM, 4), blk, 0, stream>>>(
        q_w, q_lb, q_b, k_w, k_lb, k_b, v_w, v_lb, v_b, o_w, o_lb, o_b, Wg);
    gemm_qkv_kernel<<<dim3(E_DIM / 128, NROW / 128, 3), blk, 0, stream>>>(Xg, Wg, qkv);

    flash_mfma_kernel<<<dim3(T_LEN / 128, B_SZ * N_HEADS), blk, 0, stream>>>(
        qp, kp, vpt, Xg, lbuf);
    attnw_mfma_kernel<<<dim3(S_LEN / 64, T_LEN / 128, B_SZ), blk, 0, stream>>>(
        qp, kp, lbuf, aw);

    lora_a_bf16_kernel<<<NROW / 16, blk, 0, stream>>>(Xg, o_la);
    gemm_o_kernel<<<dim3(E_DIM / 128, NROW / 64), blk, 0, stream>>>(
        Xg, Wg + 3 * WG_N, out);
}

// Round 13
// 328.246 us; speedup vs baseline: 1.0766x; 1.0766x over previous
//
#include <hip/hip_runtime.h>
#include <stdint.h>

// Problem constants
#define E_DIM 1024
#define KAUG 1056            // 1024 + 16 (LoRA) + 1 (bias) + 15 pad
#define N_HEADS 16
#define HD 64
#define R_LORA 16
#define T_LEN 2048
#define B_SZ 2
#define S_LEN 2048
#define NROW 4096            // T*B == S*B
// q pre-scale: (1/sqrt(64)) * log2(e)  -> softmax becomes exp2(score)
#define Q_SCALE 0.1803368801111204f

#define XG_N ((size_t)NROW * KAUG)
#define WG_N ((size_t)E_DIM * KAUG)
#define HSZ  ((size_t)B_SZ * N_HEADS * T_LEN * HD)

typedef unsigned short USH;
typedef __bf16 bf16x8 __attribute__((ext_vector_type(8)));
typedef unsigned short ushort8 __attribute__((ext_vector_type(8)));
typedef float  f32x4  __attribute__((ext_vector_type(4)));
typedef float  f32x16 __attribute__((ext_vector_type(16)));
typedef unsigned int u32x2 __attribute__((ext_vector_type(2)));
typedef unsigned int u32x4 __attribute__((ext_vector_type(4)));

__device__ __forceinline__ USH f2bf(float f) {
    uint32_t u = __builtin_bit_cast(uint32_t, f);
    return (USH)((u + 0x7FFFu + ((u >> 16) & 1u)) >> 16);
}
__device__ __forceinline__ float bf2f(USH s) {
    uint32_t u = ((uint32_t)s) << 16;
    return __builtin_bit_cast(float, u);
}
__device__ __forceinline__ void async_cp16(const void* g, void* l) {
    __builtin_amdgcn_global_load_lds(
        (const __attribute__((address_space(1))) void*)g,
        (__attribute__((address_space(3))) void*)l, 16, 0, 0);
}
// pack hi16(x), hi16(y) -> dword (bf16 truncation; y in high half)
__device__ __forceinline__ uint32_t pack_bf_trunc(float x, float y) {
    return __builtin_amdgcn_perm(__builtin_bit_cast(uint32_t, y),
                                 __builtin_bit_cast(uint32_t, x), 0x07060302u);
}
// 8 floats -> bf16x8 with RNE rounding (matches f2bf store path)
__device__ __forceinline__ bf16x8 cvt8(float4 a, float4 b) {
    ushort8 u;
    u[0] = f2bf(a.x); u[1] = f2bf(a.y); u[2] = f2bf(a.z); u[3] = f2bf(a.w);
    u[4] = f2bf(b.x); u[5] = f2bf(b.y); u[6] = f2bf(b.z); u[7] = f2bf(b.w);
    return __builtin_bit_cast(bf16x8, u);
}

// ---------------------------------------------------------------------------
// lora_aug v2: MFMA-based. Block = 16 rows, 4 waves K-split (256 k each).
// ---------------------------------------------------------------------------
__global__ __launch_bounds__(256) void lora_aug_x3_kernel(
    const float* __restrict__ Xq, const float* __restrict__ Xk,
    const float* __restrict__ Xv,
    const float* __restrict__ laq, const float* __restrict__ lak,
    const float* __restrict__ lav, USH* __restrict__ Xg_base) {
    int n0 = blockIdx.x * 16, y = blockIdx.y, tid = threadIdx.x;
    const float* X  = (y == 0) ? Xq : (y == 1) ? Xk : Xv;
    const float* la = (y == 0) ? laq : (y == 1) ? lak : lav;
    USH* Xg = Xg_base + (size_t)y * XG_N;

    int w = tid >> 6, lane = tid & 63, quad = lane >> 4, l16 = lane & 15;

    const float* xrow = X + (size_t)(n0 + l16) * E_DIM;
    const float* lrow = la + (size_t)l16 * E_DIM;
    USH* grow = Xg + (size_t)(n0 + l16) * KAUG;

    const f32x4 fzero = {0.f, 0.f, 0.f, 0.f};
    f32x4 acc = fzero;

#pragma unroll
    for (int i = 0; i < 8; ++i) {
        int k = w * 256 + i * 32 + quad * 8;
        bf16x8 af = cvt8(*(const float4*)(xrow + k), *(const float4*)(xrow + k + 4));
        *(bf16x8*)(grow + k) = af;                       // bf16 cast-write
        bf16x8 bf_ = cvt8(*(const float4*)(lrow + k), *(const float4*)(lrow + k + 4));
        acc = __builtin_amdgcn_mfma_f32_16x16x32_bf16(af, bf_, acc, 0, 0, 0);
    }

    // combine 4 wave-partials: acc[r] = XA[row = quad*4+r][col = l16] partial
    __shared__ float red[4][16][17];
#pragma unroll
    for (int r = 0; r < 4; ++r) red[w][quad * 4 + r][l16] = acc[r];
    __syncthreads();

    int row = tid >> 4, col = tid & 15;
    float v = red[0][row][col] + red[1][row][col] + red[2][row][col] + red[3][row][col];
    USH* trow = Xg + (size_t)(n0 + row) * KAUG + 1024;
    trow[col] = f2bf(v);                                 // XA cols 1024..1039
    trow[16 + col] = (col == 0) ? f2bf(1.0f) : (USH)0;   // bias col 1040, pad 0
}

// ---------------------------------------------------------------------------
// lora_a v2 (O-input tails): same MFMA structure; A-frags load bf16 Xg rows
// directly (already cast by flash). grid (NROW/16) = 256 blocks.
// ---------------------------------------------------------------------------
__global__ __launch_bounds__(256) void lora_a_bf16_kernel(
    USH* __restrict__ Xg, const float* __restrict__ la) {
    int n0 = blockIdx.x * 16, tid = threadIdx.x;
    int w = tid >> 6, lane = tid & 63, quad = lane >> 4, l16 = lane & 15;

    const USH* grow = Xg + (size_t)(n0 + l16) * KAUG;
    const float* lrow = la + (size_t)l16 * E_DIM;

    const f32x4 fzero = {0.f, 0.f, 0.f, 0.f};
    f32x4 acc = fzero;

#pragma unroll
    for (int i = 0; i < 8; ++i) {
        int k = w * 256 + i * 32 + quad * 8;
        bf16x8 af = *(const bf16x8*)(grow + k);
        bf16x8 bf_ = cvt8(*(const float4*)(lrow + k), *(const float4*)(lrow + k + 4));
        acc = __builtin_amdgcn_mfma_f32_16x16x32_bf16(af, bf_, acc, 0, 0, 0);
    }

    __shared__ float red[4][16][17];
#pragma unroll
    for (int r = 0; r < 4; ++r) red[w][quad * 4 + r][l16] = acc[r];
    __syncthreads();

    int row = tid >> 4, col = tid & 15;
    float v = red[0][row][col] + red[1][row][col] + red[2][row][col] + red[3][row][col];
    USH* trow = Xg + (size_t)(n0 + row) * KAUG + 1024;
    trow[col] = f2bf(v);
    trow[16 + col] = (col == 0) ? f2bf(1.0f) : (USH)0;
}

// ---------------------------------------------------------------------------
// Fused weight augment for all four projections. grid (E_DIM, 4): q,k,v,o.
// ---------------------------------------------------------------------------
__global__ __launch_bounds__(256) void aug_w4_kernel(
    const float* __restrict__ Wq, const float* __restrict__ lbq, const float* __restrict__ bq,
    const float* __restrict__ Wk, const float* __restrict__ lbk, const float* __restrict__ bk_,
    const float* __restrict__ Wv, const float* __restrict__ lbv, const float* __restrict__ bv_,
    const float* __restrict__ Wo, const float* __restrict__ lbo, const float* __restrict__ bo,
    USH* __restrict__ Wg_base) {
    int e = blockIdx.x, y = blockIdx.y, tid = threadIdx.x;
    const float* W    = (y == 0) ? Wq : (y == 1) ? Wk : (y == 2) ? Wv : Wo;
    const float* lb   = (y == 0) ? lbq : (y == 1) ? lbk : (y == 2) ? lbv : lbo;
    const float* bias = (y == 0) ? bq : (y == 1) ? bk_ : (y == 2) ? bv_ : bo;
    USH* Wg = Wg_base + (size_t)y * WG_N;

    float4 v = *(const float4*)(W + (size_t)e * E_DIM + tid * 4);
    ushort4 o;
    o.x = f2bf(v.x); o.y = f2bf(v.y); o.z = f2bf(v.z); o.w = f2bf(v.w);
    *(ushort4*)(Wg + (size_t)e * KAUG + tid * 4) = o;
    if (tid < 32) {
        float t = (tid < R_LORA) ? lb[(size_t)e * R_LORA + tid]
                                 : (tid == R_LORA ? bias[e] : 0.0f);
        Wg[(size_t)e * KAUG + 1024 + tid] = f2bf(t);
    }
}

// ---------------------------------------------------------------------------
// Batched q/k/v GEMM, 128x128 tile, grid (8, 32, 3) = 768. Double-buffered
// LDS + prefetch-before-compute + ONE barrier per K-step.
// ---------------------------------------------------------------------------
__global__ __launch_bounds__(256) void gemm_qkv_kernel(
    const USH* __restrict__ Xg_base, const USH* __restrict__ Wg_base,
    USH* __restrict__ qkv_base) {
    __shared__ __align__(16) USH As[2][128 * 32];
    __shared__ __align__(16) USH Bs[2][128 * 32];

    int orig = blockIdx.x + (blockIdx.y << 3) + blockIdx.z * 256;   // grid 8x32x3
    int v_ = (orig & 7) * 96 + (orig >> 3);                          // bijective, 768%8==0
    int e0 = (v_ & 7) * 128, n0 = ((v_ >> 3) & 31) * 128, z = v_ >> 8;

    const USH* Xg = Xg_base + (size_t)z * XG_N;
    const USH* Wg = Wg_base + (size_t)z * WG_N;
    USH* out = qkv_base + (size_t)z * HSZ;
    float scale = (z == 0) ? Q_SCALE : 1.0f;

    int tid = threadIdx.x;
    int wid = tid >> 6, lane = tid & 63, quad = lane >> 4, l16 = lane & 15;
    int wm = wid & 1, wn = wid >> 1;

    int r0 = wid * 16 + (lane >> 2);
    int k8 = (lane & 3) * 8;

    f32x4 acc[4][4];
    const f32x4 fzero = {0.f, 0.f, 0.f, 0.f};
#pragma unroll
    for (int i = 0; i < 4; ++i)
#pragma unroll
        for (int j = 0; j < 4; ++j) acc[i][j] = fzero;

    // prologue: stage kt=0 into buf 0
    async_cp16(Xg + (size_t)(n0 + r0) * KAUG + k8,       As[0] + (wid * 16) * 32);
    async_cp16(Xg + (size_t)(n0 + 64 + r0) * KAUG + k8,  As[0] + (64 + wid * 16) * 32);
    async_cp16(Wg + (size_t)(e0 + r0) * KAUG + k8,       Bs[0] + (wid * 16) * 32);
    async_cp16(Wg + (size_t)(e0 + 64 + r0) * KAUG + k8,  Bs[0] + (64 + wid * 16) * 32);
    __syncthreads();

    int cur = 0;
    for (int kt = 0; kt < KAUG; kt += 32, cur ^= 1) {
        if (kt + 32 < KAUG) {
            int kn = kt + 32;
            async_cp16(Xg + (size_t)(n0 + r0) * KAUG + kn + k8,       As[cur ^ 1] + (wid * 16) * 32);
            async_cp16(Xg + (size_t)(n0 + 64 + r0) * KAUG + kn + k8,  As[cur ^ 1] + (64 + wid * 16) * 32);
            async_cp16(Wg + (size_t)(e0 + r0) * KAUG + kn + k8,       Bs[cur ^ 1] + (wid * 16) * 32);
            async_cp16(Wg + (size_t)(e0 + 64 + r0) * KAUG + kn + k8,  Bs[cur ^ 1] + (64 + wid * 16) * 32);
        }

        bf16x8 af[4], bfr[4];
#pragma unroll
        for (int i = 0; i < 4; ++i)
            af[i] = *(const bf16x8*)&As[cur][(wm * 64 + i * 16 + l16) * 32 + quad * 8];
#pragma unroll
        for (int j = 0; j < 4; ++j)
            bfr[j] = *(const bf16x8*)&Bs[cur][(wn * 64 + j * 16 + l16) * 32 + quad * 8];
#pragma unroll
        for (int i = 0; i < 4; ++i)
#pragma unroll
            for (int j = 0; j < 4; ++j)
                acc[i][j] = __builtin_amdgcn_mfma_f32_16x16x32_bf16(
                    af[i], bfr[j], acc[i][j], 0, 0, 0);

        // one barrier: drains prefetch (landed under compute) + releases cur
        __syncthreads();
    }

#pragma unroll
    for (int i = 0; i < 4; ++i) {
#pragma unroll
        for (int j = 0; j < 4; ++j) {
#pragma unroll
            for (int r = 0; r < 4; ++r) {
                int nr = n0 + wm * 64 + i * 16 + quad * 4 + r;
                int ec = e0 + wn * 64 + j * 16 + l16;
                float v = acc[i][j][r] * scale;
                int b = nr & 1, h = ec >> 6, d = ec & 63;
                if (z != 2) {
                    int t = nr >> 1;
                    out[(((size_t)(b * 16 + h) * T_LEN + t) << 6) + d] = f2bf(v);
                } else {
                    int s = nr >> 1;
                    out[(((size_t)(b * 16 + h) * HD + d) << 11) + s] = f2bf(v);
                }
            }
        }
    }
}

// ---------------------------------------------------------------------------
// O-projection GEMM -> fp32 d_out. grid (8, 64) = 512 blocks. Pipelined
// single-barrier loop (dbuf LDS: 2x(4+8) = 24 KB).
// ---------------------------------------------------------------------------
__global__ __launch_bounds__(256) void gemm_o_kernel(
    const USH* __restrict__ Xg, const USH* __restrict__ Wg,
    float* __restrict__ out) {
    __shared__ __align__(16) USH As[2][64 * 32];
    __shared__ __align__(16) USH Bs[2][128 * 32];

    int orig = blockIdx.x + (blockIdx.y << 3);          // grid 8x64
    int v_ = ((orig & 7) << 6) + (orig >> 3);           // 64 blocks/XCD
    int e0 = (v_ & 7) * 128, n0 = (v_ >> 3) * 64;

    int tid = threadIdx.x;
    int wid = tid >> 6, lane = tid & 63, quad = lane >> 4, l16 = lane & 15;
    int wm = wid & 1, wn = wid >> 1;
    int r0 = wid * 16 + (lane >> 2);
    int k8 = (lane & 3) * 8;

    f32x4 acc[2][4];
    const f32x4 fzero = {0.f, 0.f, 0.f, 0.f};
#pragma unroll
    for (int i = 0; i < 2; ++i)
#pragma unroll
        for (int j = 0; j < 4; ++j) acc[i][j] = fzero;

    // prologue: stage kt=0 into buf 0
    async_cp16(Xg + (size_t)(n0 + r0) * KAUG + k8,       As[0] + (wid * 16) * 32);
    async_cp16(Wg + (size_t)(e0 + r0) * KAUG + k8,       Bs[0] + (wid * 16) * 32);
    async_cp16(Wg + (size_t)(e0 + 64 + r0) * KAUG + k8,  Bs[0] + (64 + wid * 16) * 32);
    __syncthreads();

    int cur = 0;
    for (int kt = 0; kt < KAUG; kt += 32, cur ^= 1) {
        if (kt + 32 < KAUG) {
            int kn = kt + 32;
            async_cp16(Xg + (size_t)(n0 + r0) * KAUG + kn + k8,       As[cur ^ 1] + (wid * 16) * 32);
            async_cp16(Wg + (size_t)(e0 + r0) * KAUG + kn + k8,       Bs[cur ^ 1] + (wid * 16) * 32);
            async_cp16(Wg + (size_t)(e0 + 64 + r0) * KAUG + kn + k8,  Bs[cur ^ 1] + (64 + wid * 16) * 32);
        }

        bf16x8 af[2], bfr[4];
#pragma unroll
        for (int i = 0; i < 2; ++i)
            af[i] = *(const bf16x8*)&As[cur][(wm * 32 + i * 16 + l16) * 32 + quad * 8];
#pragma unroll
        for (int j = 0; j < 4; ++j)
            bfr[j] = *(const bf16x8*)&Bs[cur][(wn * 64 + j * 16 + l16) * 32 + quad * 8];
#pragma unroll
        for (int i = 0; i < 2; ++i)
#pragma unroll
            for (int j = 0; j < 4; ++j)
                acc[i][j] = __builtin_amdgcn_mfma_f32_16x16x32_bf16(
                    af[i], bfr[j], acc[i][j], 0, 0, 0);

        __syncthreads();
    }

#pragma unroll
    for (int i = 0; i < 2; ++i)
#pragma unroll
        for (int j = 0; j < 4; ++j)
#pragma unroll
            for (int r = 0; r < 4; ++r) {
                int nr = n0 + wm * 32 + i * 16 + quad * 4 + r;
                int ec = e0 + wn * 64 + j * 16 + l16;
                out[(size_t)nr * E_DIM + ec] = acc[i][j][r];
            }
}

// ---------------------------------------------------------------------------
// Flash v14 (frozen): 32x32 MFMA, in-register softmax (T12), PV-lag (T15),
// fragment-major K/V staging (0 bank conflicts), one barrier/iter, XCD chunk.
// 4 waves x 32 t-rows, grid (T/128, B*H) = 512 blocks, LDS 32 KB.
// ---------------------------------------------------------------------------
__global__ __launch_bounds__(256, 2) void flash_mfma_kernel(
    const USH* __restrict__ qp, const USH* __restrict__ kp,
    const USH* __restrict__ vpt, USH* __restrict__ ohg,
    float* __restrict__ lbuf) {
    __shared__ __align__(16) USH Ks[2][4096];   // 8 frags x 512 USH (1KB each)
    __shared__ __align__(16) USH Vs[2][4096];

    int orig = blockIdx.x + (blockIdx.y << 4);  // grid 16x32
    int v_ = ((orig & 7) << 6) + (orig >> 3);   // 64 blocks/XCD chunk
    int t0 = (v_ & 15) * 128, bh = v_ >> 4;     // chunk c -> heads [4c, 4c+4)

    int tid = threadIdx.x, w = tid >> 6, lane = tid & 63;
    int lo = lane & 31, hi = lane >> 5;
    size_t headO = (size_t)bh * (T_LEN * HD);
    int t_base = t0 + w * 32;

    // Q fragments direct from global (B-operand: n=t=lo, k=kb*16+hi*8+e)
    bf16x8 bq[4];
    {
        const USH* qrow = qp + headO + (size_t)(t_base + lo) * HD + hi * 8;
#pragma unroll
        for (int kb = 0; kb < 4; ++kb)
            bq[kb] = *(const bf16x8*)(qrow + kb * 16);
    }

    // prologue: stage K[0] only (V[0] staged inside iter 0).
#pragma unroll
    for (int c = 0; c < 2; ++c) {
        int f = w * 2 + c;
        async_cp16(kp + headO + (size_t)((f >> 2) * 32 + lo) * HD + (f & 3) * 16 + hi * 8,
                   &Ks[0][f * 512]);
    }
    __syncthreads();

    const f32x16 z16 = {0,0,0,0,0,0,0,0,0,0,0,0,0,0,0,0};
    f32x16 o0 = z16, o1 = z16;
    float lsum = 0.f;
    bf16x8 pa_prev[4];          // P(i-1) A-frags, static-indexed (rule #20)

    for (int it = 0; it < S_LEN / 64; ++it) {
        int cur = it & 1;
        // prefetch K[it+1] -> Ks[cur^1]; stage V[it] -> Vs[cur]
        if (it + 1 < S_LEN / 64) {
            int sn = (it + 1) * 64;
#pragma unroll
            for (int c = 0; c < 2; ++c) {
                int f = w * 2 + c;
                async_cp16(kp + headO + (size_t)(sn + (f >> 2) * 32 + lo) * HD + (f & 3) * 16 + hi * 8,
                           &Ks[cur ^ 1][f * 512]);
            }
        }
        {
            int s0 = it * 64;
#pragma unroll
            for (int c = 0; c < 2; ++c) {
                int f = w * 2 + c;
                async_cp16(vpt + headO + (size_t)((f >> 2) * 32 + lo) * S_LEN + s0 + (f & 3) * 16 + hi * 8,
                           &Vs[cur][f * 512]);
            }
        }

        // QK^T swapped: sc[st] = 32x32 tile, C[row=s_local][col=t_local=lo]
        f32x16 sc0 = z16, sc1 = z16;
        __builtin_amdgcn_s_setprio(1);
#pragma unroll
        for (int kb = 0; kb < 4; ++kb) {
            bf16x8 ak0 = *(const bf16x8*)&Ks[cur][(0 * 4 + kb) * 512 + lane * 8];
            sc0 = __builtin_amdgcn_mfma_f32_32x32x16_bf16(ak0, bq[kb], sc0, 0, 0, 0);
        }
#pragma unroll
        for (int kb = 0; kb < 4; ++kb) {
            bf16x8 ak1 = *(const bf16x8*)&Ks[cur][(1 * 4 + kb) * 512 + lane * 8];
            sc1 = __builtin_amdgcn_mfma_f32_32x32x16_bf16(ak1, bq[kb], sc1, 0, 0, 0);
        }

        // PV(it-1): pa_prev (regs) x V(it-1) from Vs[cur^1].
        if (it > 0) {
#pragma unroll
            for (int ks = 0; ks < 4; ++ks) {
                bf16x8 bv0 = *(const bf16x8*)&Vs[cur ^ 1][(0 * 4 + ks) * 512 + lane * 8];
                o0 = __builtin_amdgcn_mfma_f32_32x32x16_bf16(pa_prev[ks], bv0, o0, 0, 0, 0);
            }
#pragma unroll
            for (int ks = 0; ks < 4; ++ks) {
                bf16x8 bv1 = *(const bf16x8*)&Vs[cur ^ 1][(1 * 4 + ks) * 512 + lane * 8];
                o1 = __builtin_amdgcn_mfma_f32_32x32x16_bf16(pa_prev[ks], bv1, o1, 0, 0, 0);
            }
        }
        __builtin_amdgcn_s_setprio(0);

        // softmax(it): exp2 in place, partial sums
        float ls0 = 0.f, ls1 = 0.f, ls2 = 0.f, ls3 = 0.f;
#pragma unroll
        for (int r = 0; r < 16; ++r) {
            float p0 = __builtin_amdgcn_exp2f(sc0[r]);
            float p1 = __builtin_amdgcn_exp2f(sc1[r]);
            sc0[r] = p0; sc1[r] = p1;
            if ((r & 3) == 0)      { ls0 += p0; ls0 += p1; }
            else if ((r & 3) == 1) { ls1 += p0; ls1 += p1; }
            else if ((r & 3) == 2) { ls2 += p0; ls2 += p1; }
            else                   { ls3 += p0; ls3 += p1; }
        }
        lsum += (ls0 + ls1) + (ls2 + ls3);

        // P(it) -> pa_prev for next iter (T12 cvt_pk + permlane32_swap)
#pragma unroll
        for (int st = 0; st < 2; ++st) {
#pragma unroll
            for (int hh = 0; hh < 2; ++hh) {
                const f32x16& s_ = st ? sc1 : sc0;
                uint32_t a0 = pack_bf_trunc(s_[hh * 8 + 0], s_[hh * 8 + 1]);
                uint32_t a1 = pack_bf_trunc(s_[hh * 8 + 2], s_[hh * 8 + 3]);
                uint32_t a2 = pack_bf_trunc(s_[hh * 8 + 4], s_[hh * 8 + 5]);
                uint32_t a3 = pack_bf_trunc(s_[hh * 8 + 6], s_[hh * 8 + 7]);
                u32x2 r02 = __builtin_amdgcn_permlane32_swap(a0, a2, false, false);
                u32x2 r13 = __builtin_amdgcn_permlane32_swap(a1, a3, false, false);
                u32x4 pd = {r02[0], r13[0], r02[1], r13[1]};
                pa_prev[st * 2 + hh] = __builtin_bit_cast(bf16x8, pd);
            }
        }

        // one barrier/iter: drains K[it+1] + V[it] staging, releases buffers
        __syncthreads();
    }

    // epilogue: PV(31) from Vs[1]
    {
#pragma unroll
        for (int ks = 0; ks < 4; ++ks) {
            bf16x8 bv0 = *(const bf16x8*)&Vs[1][(0 * 4 + ks) * 512 + lane * 8];
            o0 = __builtin_amdgcn_mfma_f32_32x32x16_bf16(pa_prev[ks], bv0, o0, 0, 0, 0);
        }
#pragma unroll
        for (int ks = 0; ks < 4; ++ks) {
            bf16x8 bv1 = *(const bf16x8*)&Vs[1][(1 * 4 + ks) * 512 + lane * 8];
            o1 = __builtin_amdgcn_mfma_f32_32x32x16_bf16(pa_prev[ks], bv1, o1, 0, 0, 0);
        }
    }

    // lane owns full row t = t_base + lo split with partner: combine halves
    lsum += __shfl_xor(lsum, 32, 64);
    float rinv = 1.0f / lsum;

    int b = bh >> 4, h = bh & 15;
    float inv[16];
#pragma unroll
    for (int r = 0; r < 16; ++r) {
        int rr = (r & 3) + 8 * (r >> 2) + 4 * hi;    // t-local of o[*][r]
        inv[r] = __shfl(rinv, rr, 64);               // lane rr holds that t
    }
#pragma unroll
    for (int r = 0; r < 16; ++r) {
        int t = t_base + (r & 3) + 8 * (r >> 2) + 4 * hi;
        size_t nrow = (size_t)(t * 2 + b) * KAUG + h * 64;
        ohg[nrow + lo]      = f2bf(o0[r] * inv[r]);
        ohg[nrow + 32 + lo] = f2bf(o1[r] * inv[r]);
    }
    if (lane < 32)
        lbuf[(size_t)bh * T_LEN + t_base + lane] = rinv;   // store 1/lsum
}

// ---------------------------------------------------------------------------
// attnw v6 (RESTORED -- best measured config, 58 us): 128t x 64s per block,
// grid = 1024 blocks. Q direct global->reg, K dbuf with next-head prefetch,
// one barrier/head, XCD-chunked swizzle, native exp2, lbuf holds 1/lsum.
// v7 (reg-dbuf Q: VGPR 172, occ 11%), v8 (Q-LDS: 48KB, FETCH 37MB), and
// v9 (head pairs: WRITE 103MB) all regressed -- v6's occupancy, per-XCD
// L2 fit, and write coalescing are mutually tuned; do not perturb.
// ---------------------------------------------------------------------------
__global__ __launch_bounds__(256, 4) void attnw_mfma_kernel(
    const USH* __restrict__ qp, const USH* __restrict__ kp,
    const float* __restrict__ lbuf, float* __restrict__ aw) {
    __shared__ __align__(16) USH Ks[2][4096];

    int orig = blockIdx.x + (blockIdx.y << 5) + (blockIdx.z << 9);  // grid 32x16x2
    int v_ = ((orig & 7) << 7) + (orig >> 3);                       // 128 blocks/XCD
    int s0 = (v_ & 31) * 64, t0 = ((v_ >> 5) & 15) * 128, b = v_ >> 9;

    int tid = threadIdx.x, w = tid >> 6, lane = tid & 63;
    int quad = lane >> 4, l16 = lane & 15;

    const f32x4 fzero = {0.f, 0.f, 0.f, 0.f};
    f32x4 acc[2][4];
#pragma unroll
    for (int i2 = 0; i2 < 2; ++i2)
#pragma unroll
        for (int j = 0; j < 4; ++j) acc[i2][j] = fzero;

    // prologue: stage K for head 0
    {
        size_t head0 = (size_t)(b * 16) * (T_LEN * HD);
#pragma unroll
        for (int half = 0; half < 2; ++half)
            async_cp16(kp + head0 + (size_t)(s0 + w * 16 + l16) * HD + half * 32 + quad * 8,
                       &Ks[0][w * 1024 + half * 512]);
    }
    __syncthreads();

    for (int h = 0; h < N_HEADS; ++h) {
        int bh = b * 16 + h;
        size_t head = (size_t)bh * (T_LEN * HD);
        int cur = h & 1;

        // prefetch next head's K into the other buffer
        if (h + 1 < N_HEADS) {
            size_t headn = head + (size_t)(T_LEN * HD);
#pragma unroll
            for (int half = 0; half < 2; ++half)
                async_cp16(kp + headn + (size_t)(s0 + w * 16 + l16) * HD + half * 32 + quad * 8,
                           &Ks[cur ^ 1][w * 1024 + half * 512]);
        }

        // Q fragments direct from global (A-operand; rows are wave-private)
        bf16x8 aq[2][2];
#pragma unroll
        for (int i2 = 0; i2 < 2; ++i2) {
            int i = w * 2 + i2;
            const USH* qrow = qp + head + (size_t)(t0 + i * 16 + l16) * HD + quad * 8;
            aq[i2][0] = *(const bf16x8*)qrow;
            aq[i2][1] = *(const bf16x8*)(qrow + 32);
        }

        float il[2][4];
#pragma unroll
        for (int i2 = 0; i2 < 2; ++i2)
#pragma unroll
            for (int r = 0; r < 4; ++r) {
                int t = t0 + w * 32 + i2 * 16 + quad * 4 + r;
                il[i2][r] = lbuf[(size_t)bh * T_LEN + t];   // already 1/lsum
            }

        bf16x8 bk[4][2];
#pragma unroll
        for (int j = 0; j < 4; ++j)
#pragma unroll
            for (int half = 0; half < 2; ++half)
                bk[j][half] = *(const bf16x8*)&Ks[cur][j * 1024 + half * 512 + quad * 128 + l16 * 8];

#pragma unroll
        for (int i2 = 0; i2 < 2; ++i2) {
#pragma unroll
            for (int j = 0; j < 4; ++j) {
                f32x4 s = __builtin_amdgcn_mfma_f32_16x16x32_bf16(aq[i2][0], bk[j][0], fzero, 0, 0, 0);
                s = __builtin_amdgcn_mfma_f32_16x16x32_bf16(aq[i2][1], bk[j][1], s, 0, 0, 0);
#pragma unroll
                for (int r = 0; r < 4; ++r)
                    acc[i2][j][r] += __builtin_amdgcn_exp2f(s[r]) * il[i2][r];
            }
        }

        // single barrier: drains this head's prefetch + releases cur buffer
        __syncthreads();
    }

    const float inv_h = 1.0f / (float)N_HEADS;
#pragma unroll
    for (int i2 = 0; i2 < 2; ++i2)
#pragma unroll
        for (int j = 0; j < 4; ++j)
#pragma unroll
            for (int r = 0; r < 4; ++r) {
                int t = t0 + w * 32 + i2 * 16 + quad * 4 + r;
                aw[(size_t)b * T_LEN * S_LEN + (size_t)t * S_LEN + s0 + j * 16 + l16] =
                    acc[i2][j][r] * inv_h;
            }
}

// ---------------------------------------------------------------------------
extern "C" void kernel_launch(void* const* d_in, const int* in_sizes, int n_in,
                              void* d_out, int out_size, void* d_ws, size_t ws_size,
                              hipStream_t stream) {
    (void)in_sizes; (void)n_in; (void)out_size; (void)ws_size;

    const float* query = (const float*)d_in[0];
    const float* key_  = (const float*)d_in[1];
    const float* value = (const float*)d_in[2];
    const float* q_w = (const float*)d_in[3],  *q_b = (const float*)d_in[4];
    const float* q_la = (const float*)d_in[5], *q_lb = (const float*)d_in[6];
    const float* k_w = (const float*)d_in[7],  *k_b = (const float*)d_in[8];
    const float* k_la = (const float*)d_in[9], *k_lb = (const float*)d_in[10];
    const float* v_w = (const float*)d_in[11], *v_b = (const float*)d_in[12];
    const float* v_la = (const float*)d_in[13], *v_lb = (const float*)d_in[14];
    const float* o_w = (const float*)d_in[15], *o_b = (const float*)d_in[16];
    const float* o_la = (const float*)d_in[17], *o_lb = (const float*)d_in[18];

    USH* Xg   = (USH*)d_ws;                 // 3 * NROW*KAUG
    USH* Wg   = Xg + 3 * XG_N;              // 4 * E_DIM*KAUG
    USH* qkv  = Wg + 4 * WG_N;              // 3 * HSZ
    USH* qp   = qkv;
    USH* kp   = qkv + HSZ;
    USH* vpt  = qkv + 2 * HSZ;
    float* lbuf = (float*)(qkv + 3 * HSZ);

    float* out = (float*)d_out;                       // (T,B,E) fp32
    float* aw  = out + (size_t)T_LEN * B_SZ * E_DIM;  // (B,T,S) fp32

    dim3 blk(256);

    lora_aug_x3_kernel<<<dim3(NROW / 16, 3), blk, 0, stream>>>(
        query, key_, value, q_la, k_la, v_la, Xg);
    aug_w4_kernel<<<dim3(E_DIM, 4), blk, 0, stream>>>(
        q_w, q_lb, q_b, k_w, k_lb, k_b, v_w, v_lb, v_b, o_w, o_lb, o_b, Wg);
    gemm_qkv_kernel<<<dim3(E_DIM / 128, NROW / 128, 3), blk, 0, stream>>>(Xg, Wg, qkv);

    flash_mfma_kernel<<<dim3(T_LEN / 128, B_SZ * N_HEADS), blk, 0, stream>>>(
        qp, kp, vpt, Xg, lbuf);
    attnw_mfma_kernel<<<dim3(S_LEN / 64, T_LEN / 128, B_SZ), blk, 0, stream>>>(
        qp, kp, lbuf, aw);

    lora_a_bf16_kernel<<<NROW / 16, blk, 0, stream>>>(Xg, o_la);
    gemm_o_kernel<<<dim3(E_DIM / 128, NROW / 64), blk, 0, stream>>>(
        Xg, Wg + 3 * WG_N, out);
}